// Round 2
// baseline (276.355 us; speedup 1.0000x reference)
//
#include <hip/hip_runtime.h>
#include <string.h>

typedef __bf16 bf16;
typedef __bf16 bf16x4 __attribute__((ext_vector_type(4)));
typedef __bf16 bf16x8 __attribute__((ext_vector_type(8)));
typedef float f32x4 __attribute__((ext_vector_type(4)));

#define BN_EPS 1e-5f
#define NORM_EPS 1e-12f

static __device__ inline unsigned int pack_bf16x2(float a, float b) {
  bf16 ha = (bf16)a, hb = (bf16)b;
  unsigned short ua, ub;
  memcpy(&ua, &ha, 2); memcpy(&ub, &hb, 2);
  return (unsigned int)ua | ((unsigned int)ub << 16);
}

// ---- prep: Ct[k][d] = clusters[d][k] * bn_scale[k] (first 64 cols); zero a_sum ----
// inputs fp32 (reference dtype), Ct bf16 (our MFMA operand)
__global__ __launch_bounds__(256) void k_prep(const float* __restrict__ clusters,
                                              const float* __restrict__ bnw,
                                              const float* __restrict__ bnv,
                                              bf16* __restrict__ Ct,
                                              float* __restrict__ asum) {
  int idx = blockIdx.x * 256 + threadIdx.x;   // 0..32767 (= 64*512)
  if (idx < 64 * 64) asum[idx] = 0.f;
  int k = idx >> 9, d = idx & 511;
  float scale = bnw[k] / sqrtf(bnv[k] + BN_EPS);
  Ct[idx] = (bf16)(clusters[d * 80 + k] * scale);
}

// ---- assign: logits GEMM + softmax(64) + At[b][k][n] (transposed) + a_sum ----
__global__ __launch_bounds__(256) void k_assign(const float* __restrict__ x,
                                                const bf16* __restrict__ Ct,
                                                bf16* __restrict__ At,
                                                float* __restrict__ asum_g) {
  __shared__ __align__(16) bf16 Xl[128 * 72];   // 128 rows x 64 d, pitch 72
  __shared__ __align__(16) bf16 Cl[64 * 72];    // 64 clusters x 64 d, pitch 72
  __shared__ float asum_l[64];
  const int t = threadIdx.x;
  const int w = t >> 6;          // wave 0..3
  const int l = t & 63;
  const int q = l >> 4;          // quad 0..3
  const int m16 = l & 15;
  const int blk = blockIdx.x;
  const int b = blk >> 3;
  const int n0 = (blk & 7) << 7; // n offset within batch
  const int row0 = blk << 7;     // global flat row

  if (t < 64) asum_l[t] = 0.f;

  f32x4 acc[2][4];
#pragma unroll
  for (int i = 0; i < 2; ++i)
#pragma unroll
    for (int j = 0; j < 4; ++j)
      acc[i][j] = (f32x4){0.f, 0.f, 0.f, 0.f};

  for (int d0 = 0; d0 < 512; d0 += 64) {
#pragma unroll
    for (int p = 0; p < 8; ++p) {           // stage X: 128 rows x 64 d fp32 -> bf16
      int id = p * 256 + t;                  // 0..2047
      int r = id >> 4, c = id & 15;          // c = 4-float chunk
      float4 v = *(const float4*)(x + (size_t)(row0 + r) * 512 + d0 + c * 4);
      bf16x4 pk;
      pk[0] = (bf16)v.x; pk[1] = (bf16)v.y; pk[2] = (bf16)v.z; pk[3] = (bf16)v.w;
      *(bf16x4*)(&Xl[r * 72 + c * 4]) = pk;  // byte off r*144+c*8, 8B aligned
    }
#pragma unroll
    for (int p = 0; p < 2; ++p) {           // stage C tile (bf16): 64 rows x 64 d
      int id = p * 256 + t;
      int r = id >> 3, c = id & 7;
      uint4 v = *(const uint4*)(Ct + r * 512 + d0 + c * 8);
      *(uint4*)(&Cl[r * 72 + c * 8]) = v;
    }
    __syncthreads();
#pragma unroll
    for (int ks = 0; ks < 2; ++ks) {
      bf16x8 bfrag[4];
#pragma unroll
      for (int nt = 0; nt < 4; ++nt)
        bfrag[nt] = *(const bf16x8*)(&Cl[(nt * 16 + m16) * 72 + ks * 32 + q * 8]);
#pragma unroll
      for (int mt = 0; mt < 2; ++mt) {
        bf16x8 afrag = *(const bf16x8*)(&Xl[(w * 32 + mt * 16 + m16) * 72 + ks * 32 + q * 8]);
#pragma unroll
        for (int nt = 0; nt < 4; ++nt)
          acc[mt][nt] = __builtin_amdgcn_mfma_f32_16x16x32_bf16(afrag, bfrag[nt], acc[mt][nt], 0, 0, 0);
      }
    }
    __syncthreads();
  }

  // epilogue: softmax over the 64 real clusters (ghost cols 64..79 never computed).
  // C/D layout per 16x16 tile: row = q*4 + reg, col = m16  [m89-verified]
  bf16* Tl = Xl;  // alias, safe: all MFMA LDS reads done before last __syncthreads
  float csum[4] = {0.f, 0.f, 0.f, 0.f};
#pragma unroll
  for (int mt = 0; mt < 2; ++mt) {
#pragma unroll
    for (int r = 0; r < 4; ++r) {
      float v[4];
#pragma unroll
      for (int nt = 0; nt < 4; ++nt) v[nt] = acc[mt][nt][r];
      float mx = fmaxf(fmaxf(v[0], v[1]), fmaxf(v[2], v[3]));
#pragma unroll
      for (int off = 1; off < 16; off <<= 1) mx = fmaxf(mx, __shfl_xor(mx, off));
      float e[4];
      float s = 0.f;
#pragma unroll
      for (int nt = 0; nt < 4; ++nt) { e[nt] = __expf(v[nt] - mx); s += e[nt]; }
#pragma unroll
      for (int off = 1; off < 16; off <<= 1) s += __shfl_xor(s, off);
      float inv = 1.f / s;
      int nrow = w * 32 + mt * 16 + q * 4 + r;   // local n
#pragma unroll
      for (int nt = 0; nt < 4; ++nt) {
        bf16 ab = (bf16)(e[nt] * inv);
        Tl[(nt * 16 + m16) * 136 + nrow] = ab;   // transpose buffer [k][n]
        csum[nt] += (float)ab;
      }
    }
  }
#pragma unroll
  for (int nt = 0; nt < 4; ++nt) {   // reduce col sums across quads of the wave
    float cs = csum[nt];
    cs += __shfl_xor(cs, 16);
    cs += __shfl_xor(cs, 32);
    if (q == 0) atomicAdd(&asum_l[nt * 16 + m16], cs);
  }
  __syncthreads();
#pragma unroll
  for (int p = 0; p < 4; ++p) {      // coalesced At store: 64 k-rows x 128 n
    int id = p * 256 + t;
    int k = id >> 4, c = id & 15;
    *(uint4*)(At + (size_t)(b * 64 + k) * 1024 + n0 + c * 8) = *(const uint4*)(&Tl[k * 136 + c * 8]);
  }
  if (t < 64) atomicAdd(&asum_g[b * 64 + t], asum_l[t]);
}

// ---- vlad: out[b,d,k] = sum_n X[n,d]*At[k,n] - a_sum[k]*c2[d,k]  (raw fp32 into d_out) ----
__global__ __launch_bounds__(256) void k_vlad(const float* __restrict__ x,
                                              const bf16* __restrict__ At,
                                              const float* __restrict__ asum_g,
                                              const float* __restrict__ c2,
                                              float* __restrict__ out) {
  __shared__ __align__(16) bf16 Xl[64 * 130];  // 64 n x 128 d, pitch 130 (=65 dw -> bank-spread)
  __shared__ __align__(16) bf16 Bl[64 * 72];   // 64 k x 64 n, pitch 72
  const int t = threadIdx.x;
  const int w = t >> 6;
  const int l = t & 63;
  const int q = l >> 4;
  const int m16 = l & 15;
  const int b = blockIdx.x >> 2;
  const int d0 = (blockIdx.x & 3) << 7;

  f32x4 acc[2][4];
#pragma unroll
  for (int i = 0; i < 2; ++i)
#pragma unroll
    for (int j = 0; j < 4; ++j)
      acc[i][j] = (f32x4){0.f, 0.f, 0.f, 0.f};

  unsigned int* Xld = (unsigned int*)Xl;
  for (int nb = 0; nb < 1024; nb += 64) {
#pragma unroll
    for (int p = 0; p < 8; ++p) {   // stage X: 64 n x 128 d fp32 -> bf16 (dword LDS writes)
      int id = p * 256 + t;          // 0..2047
      int n = id >> 5, c = id & 31;  // c = 4-float chunk of d
      float4 v = *(const float4*)(x + (size_t)(b * 1024 + nb + n) * 512 + d0 + c * 4);
      Xld[n * 65 + c * 2]     = pack_bf16x2(v.x, v.y);
      Xld[n * 65 + c * 2 + 1] = pack_bf16x2(v.z, v.w);
    }
#pragma unroll
    for (int p = 0; p < 2; ++p) {   // stage At tile: 64 k x 64 n (bf16)
      int id = p * 256 + t;
      int k = id >> 3, c = id & 7;
      uint4 v = *(const uint4*)(At + (size_t)(b * 64 + k) * 1024 + nb + c * 8);
      *(uint4*)(&Bl[k * 72 + c * 8]) = v;
    }
    __syncthreads();
#pragma unroll
    for (int ks = 0; ks < 2; ++ks) {
      bf16x8 bfrag[4];
#pragma unroll
      for (int nt = 0; nt < 4; ++nt)
        bfrag[nt] = *(const bf16x8*)(&Bl[(nt * 16 + m16) * 72 + ks * 32 + q * 8]);
#pragma unroll
      for (int mt = 0; mt < 2; ++mt) {
        int dl = (2 * w + mt) * 16 + m16;
        bf16x8 af;
#pragma unroll
        for (int j = 0; j < 8; ++j)
          af[j] = Xl[(ks * 32 + q * 8 + j) * 130 + dl];   // Xt[d][n] gather, conflict-free (pitch 65 dw)
#pragma unroll
        for (int nt = 0; nt < 4; ++nt)
          acc[mt][nt] = __builtin_amdgcn_mfma_f32_16x16x32_bf16(af, bfrag[nt], acc[mt][nt], 0, 0, 0);
      }
    }
    __syncthreads();
  }
  float sA[4];
#pragma unroll
  for (int nt = 0; nt < 4; ++nt) sA[nt] = asum_g[b * 64 + nt * 16 + m16];
#pragma unroll
  for (int mt = 0; mt < 2; ++mt) {
#pragma unroll
    for (int r = 0; r < 4; ++r) {
      int d = d0 + (2 * w + mt) * 16 + q * 4 + r;
#pragma unroll
      for (int nt = 0; nt < 4; ++nt) {
        int k = nt * 16 + m16;
        float v = acc[mt][nt][r] - sA[nt] * c2[d * 64 + k];
        out[(size_t)(b * 512 + d) * 64 + k] = v;   // unnormalized fp32 vlad
      }
    }
  }
}

// ---- norm (in-place on out): intra-norm over d per (b,k), then global norm per b ----
__global__ __launch_bounds__(256) void k_norm(float* __restrict__ out) {
  __shared__ float ssl[4][64];
  __shared__ float scl[64];
  const int b = blockIdx.x;
  const int t = threadIdx.x;
  const int k = t & 63, sl = t >> 6;
  float* vb = out + (size_t)b * 32768;
  float ss = 0.f;
  for (int d = sl; d < 512; d += 4) {
    float v = vb[d * 64 + k];
    ss += v * v;
  }
  ssl[sl][k] = ss;
  __syncthreads();
  if (t < 64) {
    float tot = ssl[0][t] + ssl[1][t] + ssl[2][t] + ssl[3][t];
    float rinv = 1.f / fmaxf(sqrtf(tot), NORM_EPS);
    float g = tot * rinv * rinv;
#pragma unroll
    for (int off = 1; off < 64; off <<= 1) g += __shfl_xor(g, off);
    float ginv = 1.f / fmaxf(sqrtf(g), NORM_EPS);
    scl[t] = rinv * ginv;
  }
  __syncthreads();
  float sk = scl[k];
  for (int d = sl; d < 512; d += 4) {
    int i = d * 64 + k;
    vb[i] = vb[i] * sk;
  }
}

extern "C" void kernel_launch(void* const* d_in, const int* in_sizes, int n_in,
                              void* d_out, int out_size, void* d_ws, size_t ws_size,
                              hipStream_t stream) {
  const float* x        = (const float*)d_in[0];
  const float* clusters = (const float*)d_in[1];
  const float* bnw      = (const float*)d_in[2];
  // d_in[3] = bn_bias, d_in[4] = bn_mean: computed-but-never-applied in the reference.
  const float* bnv      = (const float*)d_in[5];
  const float* c2       = (const float*)d_in[6];
  float* out = (float*)d_out;
  char* ws = (char*)d_ws;
  float* asum = (float*)(ws);                 // 64*64*4       = 16384 B
  bf16*  Ct   = (bf16*)(ws + 16384);          // 64*512*2      = 65536 B
  bf16*  At   = (bf16*)(ws + 16384 + 65536);  // 64*64*1024*2  = 8388608 B
  // total ws use: 8470528 B (~8.1 MiB)

  k_prep<<<128, 256, 0, stream>>>(clusters, bnw, bnv, Ct, asum);
  k_assign<<<512, 256, 0, stream>>>(x, Ct, At, asum);
  k_vlad<<<256, 256, 0, stream>>>(x, At, asum, c2, out);
  k_norm<<<64, 256, 0, stream>>>(out);
}

// Round 3
// 242.354 us; speedup vs baseline: 1.1403x; 1.1403x over previous
//
#include <hip/hip_runtime.h>
#include <string.h>

typedef __bf16 bf16;
typedef __bf16 bf16x4 __attribute__((ext_vector_type(4)));
typedef __bf16 bf16x8 __attribute__((ext_vector_type(8)));
typedef float f32x4 __attribute__((ext_vector_type(4)));

#define BN_EPS 1e-5f
#define NORM_EPS 1e-12f

static __device__ inline unsigned int pack_bf16x2(float a, float b) {
  bf16 ha = (bf16)a, hb = (bf16)b;
  unsigned short ua, ub;
  memcpy(&ua, &ha, 2); memcpy(&ub, &hb, 2);
  return (unsigned int)ua | ((unsigned int)ub << 16);
}

// ---- prep: Ct[k][d] = clusters[d][k] * bn_scale[k] (first 64 cols); zero asum+ssq ----
__global__ __launch_bounds__(256) void k_prep(const float* __restrict__ clusters,
                                              const float* __restrict__ bnw,
                                              const float* __restrict__ bnv,
                                              bf16* __restrict__ Ct,
                                              float* __restrict__ asum,
                                              float* __restrict__ ssq) {
  int idx = blockIdx.x * 256 + threadIdx.x;   // 0..32767 (= 64*512)
  if (idx < 64 * 64) { asum[idx] = 0.f; ssq[idx] = 0.f; }
  int k = idx >> 9, d = idx & 511;
  float scale = bnw[k] / sqrtf(bnv[k] + BN_EPS);
  Ct[idx] = (bf16)(clusters[d * 80 + k] * scale);
}

// ---- assign: logits GEMM + softmax(64) + At[b][k][n] (transposed) + a_sum ----
// (unchanged from round 2 — verified correct, near HBM floor on the 134 MB x read)
__global__ __launch_bounds__(256) void k_assign(const float* __restrict__ x,
                                                const bf16* __restrict__ Ct,
                                                bf16* __restrict__ At,
                                                float* __restrict__ asum_g) {
  __shared__ __align__(16) bf16 Xl[128 * 72];   // 128 rows x 64 d, pitch 72
  __shared__ __align__(16) bf16 Cl[64 * 72];    // 64 clusters x 64 d, pitch 72
  __shared__ float asum_l[64];
  const int t = threadIdx.x;
  const int w = t >> 6;          // wave 0..3
  const int l = t & 63;
  const int q = l >> 4;          // quad 0..3
  const int m16 = l & 15;
  const int blk = blockIdx.x;
  const int b = blk >> 3;
  const int n0 = (blk & 7) << 7; // n offset within batch
  const int row0 = blk << 7;     // global flat row

  if (t < 64) asum_l[t] = 0.f;

  f32x4 acc[2][4];
#pragma unroll
  for (int i = 0; i < 2; ++i)
#pragma unroll
    for (int j = 0; j < 4; ++j)
      acc[i][j] = (f32x4){0.f, 0.f, 0.f, 0.f};

  for (int d0 = 0; d0 < 512; d0 += 64) {
#pragma unroll
    for (int p = 0; p < 8; ++p) {           // stage X: 128 rows x 64 d fp32 -> bf16
      int id = p * 256 + t;                  // 0..2047
      int r = id >> 4, c = id & 15;          // c = 4-float chunk
      float4 v = *(const float4*)(x + (size_t)(row0 + r) * 512 + d0 + c * 4);
      bf16x4 pk;
      pk[0] = (bf16)v.x; pk[1] = (bf16)v.y; pk[2] = (bf16)v.z; pk[3] = (bf16)v.w;
      *(bf16x4*)(&Xl[r * 72 + c * 4]) = pk;
    }
#pragma unroll
    for (int p = 0; p < 2; ++p) {           // stage C tile (bf16): 64 rows x 64 d
      int id = p * 256 + t;
      int r = id >> 3, c = id & 7;
      uint4 v = *(const uint4*)(Ct + r * 512 + d0 + c * 8);
      *(uint4*)(&Cl[r * 72 + c * 8]) = v;
    }
    __syncthreads();
#pragma unroll
    for (int ks = 0; ks < 2; ++ks) {
      bf16x8 bfrag[4];
#pragma unroll
      for (int nt = 0; nt < 4; ++nt)
        bfrag[nt] = *(const bf16x8*)(&Cl[(nt * 16 + m16) * 72 + ks * 32 + q * 8]);
#pragma unroll
      for (int mt = 0; mt < 2; ++mt) {
        bf16x8 afrag = *(const bf16x8*)(&Xl[(w * 32 + mt * 16 + m16) * 72 + ks * 32 + q * 8]);
#pragma unroll
        for (int nt = 0; nt < 4; ++nt)
          acc[mt][nt] = __builtin_amdgcn_mfma_f32_16x16x32_bf16(afrag, bfrag[nt], acc[mt][nt], 0, 0, 0);
      }
    }
    __syncthreads();
  }

  // softmax over the 64 real clusters. C/D layout: row = q*4+reg, col = m16 [m89]
  bf16* Tl = Xl;  // alias, safe after last __syncthreads
  float csum[4] = {0.f, 0.f, 0.f, 0.f};
#pragma unroll
  for (int mt = 0; mt < 2; ++mt) {
#pragma unroll
    for (int r = 0; r < 4; ++r) {
      float v[4];
#pragma unroll
      for (int nt = 0; nt < 4; ++nt) v[nt] = acc[mt][nt][r];
      float mx = fmaxf(fmaxf(v[0], v[1]), fmaxf(v[2], v[3]));
#pragma unroll
      for (int off = 1; off < 16; off <<= 1) mx = fmaxf(mx, __shfl_xor(mx, off));
      float e[4];
      float s = 0.f;
#pragma unroll
      for (int nt = 0; nt < 4; ++nt) { e[nt] = __expf(v[nt] - mx); s += e[nt]; }
#pragma unroll
      for (int off = 1; off < 16; off <<= 1) s += __shfl_xor(s, off);
      float inv = 1.f / s;
      int nrow = w * 32 + mt * 16 + q * 4 + r;   // local n
#pragma unroll
      for (int nt = 0; nt < 4; ++nt) {
        bf16 ab = (bf16)(e[nt] * inv);
        Tl[(nt * 16 + m16) * 136 + nrow] = ab;   // transpose buffer [k][n]
        csum[nt] += (float)ab;
      }
    }
  }
#pragma unroll
  for (int nt = 0; nt < 4; ++nt) {
    float cs = csum[nt];
    cs += __shfl_xor(cs, 16);
    cs += __shfl_xor(cs, 32);
    if (q == 0) atomicAdd(&asum_l[nt * 16 + m16], cs);
  }
  __syncthreads();
#pragma unroll
  for (int p = 0; p < 4; ++p) {      // coalesced At store: 64 k-rows x 128 n
    int id = p * 256 + t;
    int k = id >> 4, c = id & 15;
    *(uint4*)(At + (size_t)(b * 64 + k) * 1024 + n0 + c * 8) = *(const uint4*)(&Tl[k * 136 + c * 8]);
  }
  if (t < 64) atomicAdd(&asum_g[b * 64 + t], asum_l[t]);
}

// ---- vlad: 512 blocks = (b, 64-wide d-chunk). Register-resident epilogue:
//      writes unscaled fp32 out + per-(b,k) sumsq partials into ssq. ----
__global__ __launch_bounds__(256, 2) void k_vlad(const float* __restrict__ x,
                                                 const bf16* __restrict__ At,
                                                 const float* __restrict__ asum_g,
                                                 const float* __restrict__ c2,
                                                 float* __restrict__ ssq_g,
                                                 float* __restrict__ out) {
  __shared__ __align__(16) bf16 Xl[64 * 66];   // 64 n x 64 d, pitch 66 (=33 dw, bank-spread)
  __shared__ __align__(16) bf16 Bl[64 * 72];   // 64 k x 64 n, pitch 72
  __shared__ float ssl[4][64];
  const int t = threadIdx.x;
  const int w = t >> 6;
  const int l = t & 63;
  const int q = l >> 4;
  const int m16 = l & 15;
  const int b = blockIdx.x >> 3;
  const int d0 = (blockIdx.x & 7) << 6;
  const int dl = w * 16 + m16;     // this lane's d-row within the 64-chunk

  f32x4 acc[4];
#pragma unroll
  for (int j = 0; j < 4; ++j) acc[j] = (f32x4){0.f, 0.f, 0.f, 0.f};

  unsigned int* Xld = (unsigned int*)Xl;
  for (int nb = 0; nb < 1024; nb += 64) {
#pragma unroll
    for (int p = 0; p < 4; ++p) {   // stage X: 64 n x 64 d fp32 -> bf16 (dword LDS writes)
      int id = p * 256 + t;          // 0..1023
      int n = id >> 4, c = id & 15;  // c = 4-float chunk of d
      float4 v = *(const float4*)(x + (size_t)(b * 1024 + nb + n) * 512 + d0 + c * 4);
      Xld[n * 33 + c * 2]     = pack_bf16x2(v.x, v.y);
      Xld[n * 33 + c * 2 + 1] = pack_bf16x2(v.z, v.w);
    }
#pragma unroll
    for (int p = 0; p < 2; ++p) {   // stage At tile: 64 k x 64 n (bf16)
      int id = p * 256 + t;
      int k = id >> 3, c = id & 7;
      uint4 v = *(const uint4*)(At + (size_t)(b * 64 + k) * 1024 + nb + c * 8);
      *(uint4*)(&Bl[k * 72 + c * 8]) = v;
    }
    __syncthreads();
#pragma unroll
    for (int ks = 0; ks < 2; ++ks) {
      bf16x8 bfrag[4];
#pragma unroll
      for (int nt = 0; nt < 4; ++nt)
        bfrag[nt] = *(const bf16x8*)(&Bl[(nt * 16 + m16) * 72 + ks * 32 + q * 8]);
      bf16x8 af;
#pragma unroll
      for (int j = 0; j < 8; ++j)
        af[j] = Xl[(ks * 32 + q * 8 + j) * 66 + dl];   // Xt[d][n] gather, conflict-free
#pragma unroll
      for (int nt = 0; nt < 4; ++nt)
        acc[nt] = __builtin_amdgcn_mfma_f32_16x16x32_bf16(af, bfrag[nt], acc[nt], 0, 0, 0);
    }
    __syncthreads();
  }

  // epilogue: subtract a_sum*c2, write unscaled out, accumulate sumsq per (b,k)
  float sA[4];
#pragma unroll
  for (int nt = 0; nt < 4; ++nt) sA[nt] = asum_g[b * 64 + nt * 16 + m16];
#pragma unroll
  for (int nt = 0; nt < 4; ++nt) {
    int k = nt * 16 + m16;
    float sq = 0.f;
#pragma unroll
    for (int r = 0; r < 4; ++r) {
      int d = d0 + w * 16 + q * 4 + r;          // C/D layout: row=q*4+r, col=m16
      float v = acc[nt][r] - sA[nt] * c2[d * 64 + k];
      out[(size_t)(b * 512 + d) * 64 + k] = v;
      sq += v * v;
    }
    sq += __shfl_xor(sq, 16);                    // reduce over the 4 quads (d-rows)
    sq += __shfl_xor(sq, 32);
    if (q == 0) ssl[w][k] = sq;
  }
  __syncthreads();
  if (t < 64) {
    float s = ssl[0][t] + ssl[1][t] + ssl[2][t] + ssl[3][t];
    atomicAdd(&ssq_g[b * 64 + t], s);
  }
}

// ---- scale: per-(b,k) intra-norm + per-b global norm, in-place on out ----
__global__ __launch_bounds__(256) void k_scale(const float* __restrict__ ssq,
                                               float* __restrict__ out) {
  __shared__ float sc[64];
  const int t = threadIdx.x;
  const int b = blockIdx.x >> 3;
  const int d0 = (blockIdx.x & 7) << 6;
  if (t < 64) {
    float tot = ssq[b * 64 + t];
    float rinv = 1.f / fmaxf(sqrtf(tot), NORM_EPS);
    float g = tot * rinv * rinv;     // ||v_k||^2 after intra-norm
#pragma unroll
    for (int off = 1; off < 64; off <<= 1) g += __shfl_xor(g, off);
    float ginv = 1.f / fmaxf(sqrtf(g), NORM_EPS);
    sc[t] = rinv * ginv;
  }
  __syncthreads();
  const int k = t & 63, dr = t >> 6;
  float s = sc[k];
  float* ob = out + ((size_t)b * 512 + d0) * 64;
#pragma unroll
  for (int d = dr; d < 64; d += 4) {
    int i = d * 64 + k;
    ob[i] = ob[i] * s;
  }
}

extern "C" void kernel_launch(void* const* d_in, const int* in_sizes, int n_in,
                              void* d_out, int out_size, void* d_ws, size_t ws_size,
                              hipStream_t stream) {
  const float* x        = (const float*)d_in[0];
  const float* clusters = (const float*)d_in[1];
  const float* bnw      = (const float*)d_in[2];
  // d_in[3] = bn_bias, d_in[4] = bn_mean: computed-but-never-applied in the reference.
  const float* bnv      = (const float*)d_in[5];
  const float* c2       = (const float*)d_in[6];
  float* out = (float*)d_out;
  char* ws = (char*)d_ws;
  float* asum = (float*)(ws);                          // 64*64*4      = 16384 B
  float* ssq  = (float*)(ws + 16384);                  // 64*64*4      = 16384 B
  bf16*  Ct   = (bf16*)(ws + 32768);                   // 64*512*2     = 65536 B
  bf16*  At   = (bf16*)(ws + 32768 + 65536);           // 64*64*1024*2 = 8388608 B

  k_prep<<<128, 256, 0, stream>>>(clusters, bnw, bnv, Ct, asum, ssq);
  k_assign<<<512, 256, 0, stream>>>(x, Ct, At, asum);
  k_vlad<<<512, 256, 0, stream>>>(x, At, asum, c2, ssq, out);
  k_scale<<<512, 256, 0, stream>>>(ssq, out);
}